// Round 7
// baseline (26.658 us; speedup 1.0000x reference)
//
#include <hip/hip_runtime.h>

typedef unsigned short u16;
typedef __attribute__((ext_vector_type(8))) short bf16x8;
typedef __attribute__((ext_vector_type(4))) float f32x4;

#define BATCH 16384
#define DIM   2048
#define NTASK 8
#define ODIM  128
#define KMASK 256   /* DIM / NTASK */
#define BM    64
#define NCH   4     /* 16-row chunks */

__device__ __forceinline__ int task0_id(const float* __restrict__ t) {
    int t0 = 0;
#pragma unroll
    for (int j = 1; j < NTASK; ++j)
        if (t[j] > 0.5f) t0 = j;
    return t0;
}

__device__ __forceinline__ unsigned f2bf_u(float f) {
    union { float f; unsigned u; } v; v.f = f;
    return (v.u + 0x7FFFu + ((v.u >> 16) & 1u)) >> 16;
}
__device__ __forceinline__ unsigned pack2(float a, float b) {
    return f2bf_u(a) | (f2bf_u(b) << 16);
}
__device__ __forceinline__ float dot4v(f32x4 v) {
    return v[0] * v[0] + v[1] * v[1] + v[2] * v[2] + v[3] * v[3];
}

// Single fused kernel. Per block (64 rows, 512 thr, 8 waves):
//   A (x slice, HBM) and B (centers slice, L2) streams issued back-to-back so
//   both run concurrently; A packs to swizzled LDS while B is in flight;
//   each wave converts its own B slice to bf16 regs (B-stationary, 128 VGPR);
//   then 4 x (8 ds_read_b128 + 32 MFMA + in-lane Gaussian epilogue).
__global__ __launch_bounds__(512, 2)
void fused_kernel(const float* __restrict__ task,
                  const float* __restrict__ x,
                  const float* __restrict__ centers,
                  float* __restrict__ out) {
    __shared__ u16   As[NCH][16 * KMASK];   // 32 KB, XOR-swizzled 16B slots
    __shared__ float x2s[BM];               // -0.5 * masked row norms
    __shared__ float msks[BM][NTASK];

    const int tid  = threadIdx.x;
    const int w    = tid >> 6;     // wave 0..7, o in [w*16, w*16+16)
    const int lane = tid & 63;
    const int l15  = lane & 15;
    const int g    = lane >> 4;
    const int bm   = blockIdx.x * BM;
    const int t0   = task0_id(task);

    // ---- (1) A loads: 8 float4/thread from HBM, issued first ----
    const int srow = tid >> 3;          // 0..63
    const int scol = (tid & 7) * 32;
    const float* xp = x + (size_t)(bm + srow) * DIM + t0 * KMASK + scol;
    f32x4 xa[8];
#pragma unroll
    for (int i = 0; i < 8; ++i)
        xa[i] = *reinterpret_cast<const f32x4*>(xp + i * 4);

    // ---- (2) B mega-batch 1 (c = 0,1): fp32 loads issued now so the L2
    //          stream runs concurrently with the A HBM stream ----
    const int oc0 = (w * 16 + l15) * 4;
    const float* cb = centers + (size_t)oc0 * DIM + t0 * KMASK + g * 8;
    f32x4 tb[2][16];
#pragma unroll
    for (int c = 0; c < 2; ++c)
#pragma unroll
        for (int ks = 0; ks < 8; ++ks) {
            const float* p = cb + (size_t)c * DIM + ks * 32;
            tb[c][2 * ks]     = *reinterpret_cast<const f32x4*>(p);
            tb[c][2 * ks + 1] = *reinterpret_cast<const f32x4*>(p + 4);
        }

    // masks: one float per thread covers all 64 rows x 8 tasks
    msks[srow][tid & 7] = task[(size_t)(bm + srow) * NTASK + (tid & 7)];

    // ---- (3) pack A -> LDS (swizzled) + fused x2; waits only on A ----
    float sq = 0.f;
#pragma unroll
    for (int i = 0; i < 8; ++i) sq += dot4v(xa[i]);
    sq += __shfl_xor(sq, 1);
    sq += __shfl_xor(sq, 2);
    sq += __shfl_xor(sq, 4);
    if ((tid & 7) == 0) x2s[srow] = -0.5f * sq;

    const int ch_w = srow >> 4;
    const int rr   = srow & 15;
#pragma unroll
    for (int i = 0; i < 4; ++i) {
        int4 q = make_int4(
            (int)pack2(xa[2 * i][0], xa[2 * i][1]),
            (int)pack2(xa[2 * i][2], xa[2 * i][3]),
            (int)pack2(xa[2 * i + 1][0], xa[2 * i + 1][1]),
            (int)pack2(xa[2 * i + 1][2], xa[2 * i + 1][3]));
        const int slot = (tid & 7) * 4 + i;
        const int sw   = slot ^ (rr & 7);
        *reinterpret_cast<int4*>(&As[ch_w][rr * KMASK + sw * 8]) = q;
    }
    __syncthreads();   // the kernel's single barrier (A tile complete)

    // ---- (5) convert B1 -> bv, issue+convert B2; fused w2 ----
    bf16x8 bv[4][8];
    float  w2v[4];
#pragma unroll
    for (int c = 0; c < 2; ++c) {
        float s = 0.f;
#pragma unroll
        for (int i = 0; i < 16; ++i) s += dot4v(tb[c][i]);
        s += __shfl_xor(s, 16);
        s += __shfl_xor(s, 32);
        w2v[c] = -0.5f * s;
#pragma unroll
        for (int ks = 0; ks < 8; ++ks) {
            int4 q = make_int4(
                (int)pack2(tb[c][2 * ks][0],     tb[c][2 * ks][1]),
                (int)pack2(tb[c][2 * ks][2],     tb[c][2 * ks][3]),
                (int)pack2(tb[c][2 * ks + 1][0], tb[c][2 * ks + 1][1]),
                (int)pack2(tb[c][2 * ks + 1][2], tb[c][2 * ks + 1][3]));
            bv[c][ks] = *reinterpret_cast<bf16x8*>(&q);
        }
    }
#pragma unroll
    for (int c = 2; c < 4; ++c)   // second mega-batch reuses tb storage
#pragma unroll
        for (int ks = 0; ks < 8; ++ks) {
            const float* p = cb + (size_t)c * DIM + ks * 32;
            tb[c - 2][2 * ks]     = *reinterpret_cast<const f32x4*>(p);
            tb[c - 2][2 * ks + 1] = *reinterpret_cast<const f32x4*>(p + 4);
        }
#pragma unroll
    for (int c = 2; c < 4; ++c) {
        float s = 0.f;
#pragma unroll
        for (int i = 0; i < 16; ++i) s += dot4v(tb[c - 2][i]);
        s += __shfl_xor(s, 16);
        s += __shfl_xor(s, 32);
        w2v[c] = -0.5f * s;
#pragma unroll
        for (int ks = 0; ks < 8; ++ks) {
            int4 q = make_int4(
                (int)pack2(tb[c - 2][2 * ks][0],     tb[c - 2][2 * ks][1]),
                (int)pack2(tb[c - 2][2 * ks][2],     tb[c - 2][2 * ks][3]),
                (int)pack2(tb[c - 2][2 * ks + 1][0], tb[c - 2][2 * ks + 1][1]),
                (int)pack2(tb[c - 2][2 * ks + 1][2], tb[c - 2][2 * ks + 1][3]));
            bv[c][ks] = *reinterpret_cast<bf16x8*>(&q);
        }
    }

    // ---- (6) 4 chunks: 8 ds_read_b128 + 32 MFMA + in-lane epilogue ----
#pragma unroll
    for (int ch = 0; ch < NCH; ++ch) {
        bf16x8 av[8];
#pragma unroll
        for (int ks = 0; ks < 8; ++ks)
            av[ks] = *reinterpret_cast<const bf16x8*>(
                &As[ch][l15 * KMASK + ((ks * 4 + g) ^ (l15 & 7)) * 8]);

        f32x4 acc[4];
#pragma unroll
        for (int c = 0; c < 4; ++c) acc[c] = (f32x4){0.f, 0.f, 0.f, 0.f};
#pragma unroll
        for (int ks = 0; ks < 8; ++ks)
#pragma unroll
            for (int c = 0; c < 4; ++c)
                acc[c] = __builtin_amdgcn_mfma_f32_16x16x32_bf16(
                    av[ks], bv[c][ks], acc[c], 0, 0, 0);

        // D layout: col = l15 (o), row = g*4 + r
#pragma unroll
        for (int r = 0; r < 4; ++r) {
            const int row = ch * 16 + g * 4 + r;
            const float xh = x2s[row];
            const float mk = msks[row][w];
            const float e0 = __expf(acc[0][r] + xh + w2v[0]);
            const float e1 = __expf(acc[1][r] + xh + w2v[1]);
            const float e2 = __expf(acc[2][r] + xh + w2v[2]);
            const float e3 = __expf(acc[3][r] + xh + w2v[3]);
            const float S  = e0 + e1 + e2 + e3;
            const float Mx = fmaxf(fmaxf(e0, e1), fmaxf(e2, e3));
            const float P  = S / (S + 4.0f - 4.0f * Mx);
            __builtin_nontemporal_store(
                P * mk, &out[(size_t)(bm + row) * ODIM + w * 16 + l15]);
        }
    }
}

extern "C" void kernel_launch(void* const* d_in, const int* in_sizes, int n_in,
                              void* d_out, int out_size, void* d_ws, size_t ws_size,
                              hipStream_t stream) {
    const float* task    = (const float*)d_in[0];   // [16384, 8]
    const float* x       = (const float*)d_in[1];   // [16384, 2048]
    const float* centers = (const float*)d_in[2];   // [128, 4, 2048]
    float* out = (float*)d_out;                     // [16384, 128]

    fused_kernel<<<dim3(BATCH / BM), dim3(512), 0, stream>>>(task, x, centers, out);
}

// Round 8
// 26.591 us; speedup vs baseline: 1.0025x; 1.0025x over previous
//
#include <hip/hip_runtime.h>

typedef unsigned short u16;
typedef __attribute__((ext_vector_type(8))) short bf16x8;
typedef __attribute__((ext_vector_type(4))) float f32x4;

#define BATCH 16384
#define DIM   2048
#define NTASK 8
#define ODIM  128
#define KMASK 256   /* DIM / NTASK */
#define BM    64
#define NCH   4     /* 16-row chunks */

__device__ __forceinline__ int task0_id(const float* __restrict__ t) {
    int t0 = 0;
#pragma unroll
    for (int j = 1; j < NTASK; ++j)
        if (t[j] > 0.5f) t0 = j;
    return t0;
}

__device__ __forceinline__ unsigned f2bf_u(float f) {
    union { float f; unsigned u; } v; v.f = f;
    return (v.u + 0x7FFFu + ((v.u >> 16) & 1u)) >> 16;
}
__device__ __forceinline__ unsigned pack2(float a, float b) {
    return f2bf_u(a) | (f2bf_u(b) << 16);
}
__device__ __forceinline__ float dot4v(f32x4 v) {
    return v[0] * v[0] + v[1] * v[1] + v[2] * v[2] + v[3] * v[3];
}

// load one c-batch (16 float4) of this wave-lane's B slice
#define LOADB(dst, c)                                                    \
    _Pragma("unroll")                                                    \
    for (int ks = 0; ks < 8; ++ks) {                                     \
        const float* p = cb + (size_t)(c) * DIM + ks * 32;               \
        dst[2 * ks]     = *reinterpret_cast<const f32x4*>(p);            \
        dst[2 * ks + 1] = *reinterpret_cast<const f32x4*>(p + 4);        \
    }

// convert one c-batch to bf16 frags + fused w2 (reduce over g-groups)
#define CVTB(c, src)                                                     \
    {                                                                    \
        float s = 0.f;                                                   \
        _Pragma("unroll")                                                \
        for (int i = 0; i < 16; ++i) s += dot4v(src[i]);                 \
        s += __shfl_xor(s, 16);                                          \
        s += __shfl_xor(s, 32);                                          \
        w2v[c] = -0.5f * s;                                              \
        _Pragma("unroll")                                                \
        for (int ks = 0; ks < 8; ++ks) {                                 \
            int4 q = make_int4(                                          \
                (int)pack2(src[2 * ks][0],     src[2 * ks][1]),          \
                (int)pack2(src[2 * ks][2],     src[2 * ks][3]),          \
                (int)pack2(src[2 * ks + 1][0], src[2 * ks + 1][1]),      \
                (int)pack2(src[2 * ks + 1][2], src[2 * ks + 1][3]));     \
            bv[c][ks] = *reinterpret_cast<bf16x8*>(&q);                  \
        }                                                                \
    }

// Single-node fused kernel, spill-free register plan:
//   A (HBM) + B (L2) streams issued back-to-back; A packs to swizzled LDS
//   while B is in flight; B converted in 4 c-batches through two 64-VGPR
//   buffers; 4 x (8 ds_read_b128 + 32 MFMA + in-lane Gaussian epilogue).
__global__ __launch_bounds__(512, 2)
void fused_kernel(const float* __restrict__ task,
                  const float* __restrict__ x,
                  const float* __restrict__ centers,
                  float* __restrict__ out) {
    __shared__ u16   As[NCH][16 * KMASK];   // 32 KB, XOR-swizzled 16B slots
    __shared__ float x2s[BM];
    __shared__ float msks[BM][NTASK];

    const int tid  = threadIdx.x;
    const int w    = tid >> 6;     // wave 0..7, o in [w*16, w*16+16)
    const int lane = tid & 63;
    const int l15  = lane & 15;
    const int g    = lane >> 4;
    const int bm   = blockIdx.x * BM;
    const int t0   = task0_id(task);

    // ---- (1) A loads: 8 float4/thread from HBM, issued first ----
    const int srow = tid >> 3;          // 0..63
    const int scol = (tid & 7) * 32;
    const float* xp = x + (size_t)(bm + srow) * DIM + t0 * KMASK + scol;
    f32x4 xa[8];
#pragma unroll
    for (int i = 0; i < 8; ++i)
        xa[i] = *reinterpret_cast<const f32x4*>(xp + i * 4);

    // ---- (2) B c-batches 0,1 issued now: L2 stream overlaps A's HBM ----
    const int oc0 = (w * 16 + l15) * 4;
    const float* cb = centers + (size_t)oc0 * DIM + t0 * KMASK + g * 8;
    f32x4 tba[16], tbb[16];             // two named 64-VGPR staging buffers
    LOADB(tba, 0)
    LOADB(tbb, 1)

    msks[srow][tid & 7] = task[(size_t)(bm + srow) * NTASK + (tid & 7)];

    // ---- (3) pack A -> LDS (swizzled) + fused x2; waits only on A ----
    float sq = 0.f;
#pragma unroll
    for (int i = 0; i < 8; ++i) sq += dot4v(xa[i]);
    sq += __shfl_xor(sq, 1);
    sq += __shfl_xor(sq, 2);
    sq += __shfl_xor(sq, 4);
    if ((tid & 7) == 0) x2s[srow] = -0.5f * sq;

    const int ch_w = srow >> 4;
    const int rr   = srow & 15;
#pragma unroll
    for (int i = 0; i < 4; ++i) {
        int4 q = make_int4(
            (int)pack2(xa[2 * i][0], xa[2 * i][1]),
            (int)pack2(xa[2 * i][2], xa[2 * i][3]),
            (int)pack2(xa[2 * i + 1][0], xa[2 * i + 1][1]),
            (int)pack2(xa[2 * i + 1][2], xa[2 * i + 1][3]));
        const int slot = (tid & 7) * 4 + i;
        const int sw   = slot ^ (rr & 7);
        *reinterpret_cast<int4*>(&As[ch_w][rr * KMASK + sw * 8]) = q;
    }
    __syncthreads();   // single barrier: A tile complete

    // ---- (4) B pipeline: convert batch k while batch k+1 is in flight ----
    bf16x8 bv[4][8];
    float  w2v[4];
    CVTB(0, tba)       // waits tba
    LOADB(tba, 2)
    CVTB(1, tbb)       // waits tbb
    LOADB(tbb, 3)
    CVTB(2, tba)
    CVTB(3, tbb)

    // ---- (5) 4 chunks: 8 ds_read_b128 + 32 MFMA + in-lane epilogue ----
#pragma unroll
    for (int ch = 0; ch < NCH; ++ch) {
        bf16x8 av[8];
#pragma unroll
        for (int ks = 0; ks < 8; ++ks)
            av[ks] = *reinterpret_cast<const bf16x8*>(
                &As[ch][l15 * KMASK + ((ks * 4 + g) ^ (l15 & 7)) * 8]);

        f32x4 acc[4];
#pragma unroll
        for (int c = 0; c < 4; ++c) acc[c] = (f32x4){0.f, 0.f, 0.f, 0.f};
#pragma unroll
        for (int ks = 0; ks < 8; ++ks)
#pragma unroll
            for (int c = 0; c < 4; ++c)
                acc[c] = __builtin_amdgcn_mfma_f32_16x16x32_bf16(
                    av[ks], bv[c][ks], acc[c], 0, 0, 0);

        // D layout: col = l15 (o), row = g*4 + r
#pragma unroll
        for (int r = 0; r < 4; ++r) {
            const int row = ch * 16 + g * 4 + r;
            const float xh = x2s[row];
            const float mk = msks[row][w];
            const float e0 = __expf(acc[0][r] + xh + w2v[0]);
            const float e1 = __expf(acc[1][r] + xh + w2v[1]);
            const float e2 = __expf(acc[2][r] + xh + w2v[2]);
            const float e3 = __expf(acc[3][r] + xh + w2v[3]);
            const float S  = e0 + e1 + e2 + e3;
            const float Mx = fmaxf(fmaxf(e0, e1), fmaxf(e2, e3));
            const float P  = S / (S + 4.0f - 4.0f * Mx);
            __builtin_nontemporal_store(
                P * mk, &out[(size_t)(bm + row) * ODIM + w * 16 + l15]);
        }
    }
}

extern "C" void kernel_launch(void* const* d_in, const int* in_sizes, int n_in,
                              void* d_out, int out_size, void* d_ws, size_t ws_size,
                              hipStream_t stream) {
    const float* task    = (const float*)d_in[0];   // [16384, 8]
    const float* x       = (const float*)d_in[1];   // [16384, 2048]
    const float* centers = (const float*)d_in[2];   // [128, 4, 2048]
    float* out = (float*)d_out;                     // [16384, 128]

    fused_kernel<<<dim3(BATCH / BM), dim3(512), 0, stream>>>(task, x, centers, out);
}

// Round 9
// 24.352 us; speedup vs baseline: 1.0947x; 1.0919x over previous
//
#include <hip/hip_runtime.h>

typedef unsigned short u16;
typedef __attribute__((ext_vector_type(8))) short bf16x8;
typedef __attribute__((ext_vector_type(4))) float f32x4;

#define BATCH 16384
#define DIM   2048
#define NTASK 8
#define ODIM  128
#define KMASK 256   /* DIM / NTASK */
#define OCN   512   /* ODIM * 4    */
#define BM    64
#define NCH   4     /* 16-row chunks */

__device__ __forceinline__ int task0_id(const float* __restrict__ t) {
    int t0 = 0;
#pragma unroll
    for (int j = 1; j < NTASK; ++j)
        if (t[j] > 0.5f) t0 = j;
    return t0;
}

__device__ __forceinline__ unsigned f2bf_u(float f) {
    union { float f; unsigned u; } v; v.f = f;
    return (v.u + 0x7FFFu + ((v.u >> 16) & 1u)) >> 16;
}
__device__ __forceinline__ unsigned pack2(float a, float b) {
    return f2bf_u(a) | (f2bf_u(b) << 16);
}
__device__ __forceinline__ float dot4(float4 v) {
    return v.x * v.x + v.y * v.y + v.z * v.z + v.w * v.w;
}
__device__ __forceinline__ float dot4v(f32x4 v) {
    return v[0] * v[0] + v[1] * v[1] + v[2] * v[2] + v[3] * v[3];
}

// B-only prep: centers masked slice -> c-major bf16 Bbf[c*128+o][256],
// plus w2c[c*128+o] = -0.5 * ||w||^2. 128 blocks x 256 thr, one wave per oc.
__global__ __launch_bounds__(256)
void prep_kernel(const float* __restrict__ task,
                 const float* __restrict__ centers,
                 u16* __restrict__ Bbf, float* __restrict__ w2c) {
    const int oc   = blockIdx.x * 4 + (threadIdx.x >> 6);
    const int lane = threadIdx.x & 63;
    const int t0   = task0_id(task);
    const int rowp = (oc & 3) * ODIM + (oc >> 2);   // c*128 + o
    float4 v = *reinterpret_cast<const float4*>(
        centers + (size_t)oc * DIM + t0 * KMASK + lane * 4);
    float s = dot4(v);
#pragma unroll
    for (int off = 32; off; off >>= 1) s += __shfl_xor(s, off);
    if (lane == 0) w2c[rowp] = -0.5f * s;
    ushort4 bb;
    bb.x = (u16)f2bf_u(v.x); bb.y = (u16)f2bf_u(v.y);
    bb.z = (u16)f2bf_u(v.z); bb.w = (u16)f2bf_u(v.w);
    *reinterpret_cast<ushort4*>(Bbf + (size_t)rowp * KMASK + lane * 4) = bb;
}

// Main: inline A fp32->bf16 staging (one pass over x), B-stationary bf16 regs,
// one barrier, 4 x (8 ds_read_b128 + 32 MFMA + in-lane Gaussian epilogue).
__global__ __launch_bounds__(512, 2)
void gauss_kernel(const float* __restrict__ task,
                  const float* __restrict__ x,
                  const u16* __restrict__ Bbf,
                  const float* __restrict__ w2c,
                  float* __restrict__ out) {
    __shared__ u16   As[NCH][16 * KMASK];   // 32 KB, XOR-swizzled 16B slots
    __shared__ float x2s[BM];               // -0.5 * masked row norms
    __shared__ float msks[BM][NTASK];

    const int tid  = threadIdx.x;
    const int w    = tid >> 6;     // wave 0..7, o in [w*16, w*16+16)
    const int lane = tid & 63;
    const int l15  = lane & 15;
    const int g    = lane >> 4;
    const int bm   = blockIdx.x * BM;
    const int t0   = task0_id(task);

    // ---- A loads first: 8 independent float4 from HBM (deepest latency) ----
    const int srow = tid >> 3;          // 0..63
    const int scol = (tid & 7) * 32;    // 32 floats per thread
    const float* xp = x + (size_t)(bm + srow) * DIM + t0 * KMASK + scol;
    float4 xa[8];
#pragma unroll
    for (int i = 0; i < 8; ++i)
        xa[i] = *reinterpret_cast<const float4*>(xp + i * 4);

    // ---- B loads: 32 dwordx4 of bf16 from L2 (retire under A-pack) ----
    bf16x8 bv[4][8];
    {
        const u16* bp = Bbf + (size_t)(w * 16 + l15) * KMASK + g * 8;
#pragma unroll
        for (int c = 0; c < 4; ++c)
#pragma unroll
            for (int ks = 0; ks < 8; ++ks)
                bv[c][ks] = *reinterpret_cast<const bf16x8*>(
                    bp + (size_t)c * ODIM * KMASK + ks * 32);
    }
    float w2v[4];
#pragma unroll
    for (int c = 0; c < 4; ++c) w2v[c] = w2c[c * ODIM + w * 16 + l15];

    // masks: one float per thread covers all 64 rows x 8 tasks
    msks[srow][tid & 7] = task[(size_t)(bm + srow) * NTASK + (tid & 7)];

    // ---- pack A -> LDS (swizzled) + fused x2 ----
    float sq = 0.f;
#pragma unroll
    for (int i = 0; i < 8; ++i) sq += dot4(xa[i]);
    sq += __shfl_xor(sq, 1);
    sq += __shfl_xor(sq, 2);
    sq += __shfl_xor(sq, 4);
    if ((tid & 7) == 0) x2s[srow] = -0.5f * sq;

    const int ch_w = srow >> 4;
    const int rr   = srow & 15;
#pragma unroll
    for (int i = 0; i < 4; ++i) {
        int4 q = make_int4(
            (int)pack2(xa[2 * i].x, xa[2 * i].y),
            (int)pack2(xa[2 * i].z, xa[2 * i].w),
            (int)pack2(xa[2 * i + 1].x, xa[2 * i + 1].y),
            (int)pack2(xa[2 * i + 1].z, xa[2 * i + 1].w));
        const int slot = (tid & 7) * 4 + i;
        const int sw   = slot ^ (rr & 7);
        *reinterpret_cast<int4*>(&As[ch_w][rr * KMASK + sw * 8]) = q;
    }
    __syncthreads();

    // ---- 4 chunks: ds_read + MFMA + epilogue ----
#pragma unroll
    for (int ch = 0; ch < NCH; ++ch) {
        bf16x8 av[8];
#pragma unroll
        for (int ks = 0; ks < 8; ++ks)
            av[ks] = *reinterpret_cast<const bf16x8*>(
                &As[ch][l15 * KMASK + ((ks * 4 + g) ^ (l15 & 7)) * 8]);

        f32x4 acc[4];
#pragma unroll
        for (int c = 0; c < 4; ++c) acc[c] = (f32x4){0.f, 0.f, 0.f, 0.f};
#pragma unroll
        for (int ks = 0; ks < 8; ++ks)
#pragma unroll
            for (int c = 0; c < 4; ++c)
                acc[c] = __builtin_amdgcn_mfma_f32_16x16x32_bf16(
                    av[ks], bv[c][ks], acc[c], 0, 0, 0);

        // D layout: col = l15 (o), row = g*4 + r
#pragma unroll
        for (int r = 0; r < 4; ++r) {
            const int row = ch * 16 + g * 4 + r;
            const float xh = x2s[row];
            const float mk = msks[row][w];
            const float e0 = __expf(acc[0][r] + xh + w2v[0]);
            const float e1 = __expf(acc[1][r] + xh + w2v[1]);
            const float e2 = __expf(acc[2][r] + xh + w2v[2]);
            const float e3 = __expf(acc[3][r] + xh + w2v[3]);
            const float S  = e0 + e1 + e2 + e3;
            const float Mx = fmaxf(fmaxf(e0, e1), fmaxf(e2, e3));
            const float P  = S / (S + 4.0f - 4.0f * Mx);
            __builtin_nontemporal_store(
                P * mk, &out[(size_t)(bm + row) * ODIM + w * 16 + l15]);
        }
    }
}

extern "C" void kernel_launch(void* const* d_in, const int* in_sizes, int n_in,
                              void* d_out, int out_size, void* d_ws, size_t ws_size,
                              hipStream_t stream) {
    const float* task    = (const float*)d_in[0];   // [16384, 8]
    const float* x       = (const float*)d_in[1];   // [16384, 2048]
    const float* centers = (const float*)d_in[2];   // [128, 4, 2048]
    float* out = (float*)d_out;                     // [16384, 128]

    u16*   Bbf = (u16*)d_ws;                                   // 256 KB
    float* w2c = (float*)((char*)d_ws + OCN * KMASK * 2u);     // 2 KB

    prep_kernel<<<dim3(OCN / 4), dim3(256), 0, stream>>>(task, centers, Bbf, w2c);
    gauss_kernel<<<dim3(BATCH / BM), dim3(512), 0, stream>>>(
        task, x, Bbf, w2c, out);
}